// Round 2
// baseline (2625.876 us; speedup 1.0000x reference)
//
#include <hip/hip_runtime.h>
#include <hip/hip_bf16.h>
#include <stdint.h>
#include <stddef.h>

typedef __bf16 bf16_t;
typedef __bf16 bf16x2 __attribute__((ext_vector_type(2)));
typedef __bf16 bf16x4 __attribute__((ext_vector_type(4)));
typedef __bf16 bf16x8 __attribute__((ext_vector_type(8)));
typedef float floatx4 __attribute__((ext_vector_type(4)));

#define NN 20000
#define EE 320000
#define DD 512
#define BETA1 0.6931471805599453f
#define BETA2 0.40546510810816444f

// ---------------- degree / norm ----------------
__global__ void deg_kernel(const int* __restrict__ dst, float* __restrict__ deg, int E) {
  int e = blockIdx.x * 256 + threadIdx.x;
  if (e < E) atomicAdd(&deg[dst[e]], 1.0f);
}

__global__ void norm_kernel(const float* __restrict__ deg, float* __restrict__ nrm, int n) {
  int i = blockIdx.x * 256 + threadIdx.x;
  if (i < n) nrm[i] = 1.0f / sqrtf(fmaxf(deg[i], 1.0f));
}

// ---------------- f32 -> bf16 convert (4 elems/thread) ----------------
__global__ void cvt_kernel(const float* __restrict__ in, bf16_t* __restrict__ out, int n4) {
  int i = blockIdx.x * 256 + threadIdx.x;
  if (i < n4) {
    float4 v = ((const float4*)in)[i];
    bf16x4 o = {(bf16_t)v.x, (bf16_t)v.y, (bf16_t)v.z, (bf16_t)v.w};
    ((bf16x4*)out)[i] = o;
  }
}

// -------- build BT = [W1; W2]^T (bf16), BT[n][k], n<512, k<K; W* are f32 -----
__global__ void transpose_cat(const float* __restrict__ W1, const float* __restrict__ W2,
                              bf16_t* __restrict__ BT, int K) {
  __shared__ bf16_t tile[32][33];
  int k0 = blockIdx.y * 32;
  int n0 = blockIdx.x * 32;
  int tx = threadIdx.x, ty = threadIdx.y;
  const float* W = (k0 < 512) ? W1 : W2;
  int kk = (k0 < 512) ? k0 : (k0 - 512);
#pragma unroll
  for (int i = 0; i < 32; i += 8)
    tile[ty + i][tx] = (bf16_t)W[(size_t)(kk + ty + i) * 512 + n0 + tx];
  __syncthreads();
#pragma unroll
  for (int i = 0; i < 32; i += 8)
    BT[(size_t)(n0 + ty + i) * K + k0 + tx] = tile[tx][ty + i];
}

// ------- edge scatter: agg[dst] += hin[src] * norm[src]   (hin is bf16) ------
__global__ __launch_bounds__(256) void scatter_kernel(const bf16_t* __restrict__ hin,
                                                      const float* __restrict__ nrm,
                                                      const int* __restrict__ src,
                                                      const int* __restrict__ dst,
                                                      float* __restrict__ agg) {
  int e = blockIdx.x;
  int s = src[e], t = dst[e];
  float ns = nrm[s];
  int d = threadIdx.x * 2;
  bf16x2 v = *(const bf16x2*)(hin + (size_t)s * DD + d);
  float* ap = agg + (size_t)t * DD + d;
  atomicAdd(ap, (float)v.x * ns);
  atomicAdd(ap + 1, (float)v.y * ns);
}

// ------- build A_cat = [bf16(0.9*norm*agg) | bf16(0.1*h)]  (h is bf16) -------
__global__ void prep_kernel(const float* __restrict__ agg, const bf16_t* __restrict__ h,
                            const float* __restrict__ nrm, bf16_t* __restrict__ Acat) {
  int idx = blockIdx.x * 256 + threadIdx.x;  // over NN*DD
  int i = idx >> 9, d = idx & 511;
  float nv = nrm[i];
  Acat[(size_t)i * 1024 + d]       = (bf16_t)(0.9f * nv * agg[idx]);
  Acat[(size_t)i * 1024 + 512 + d] = (bf16_t)(0.1f * (float)h[idx]);
}

// -------- GEMM: C = A(MxK,bf16) @ B(Kx512), B given transposed BT[n][k] ------
// MODE 0: h = acc + bias                      -> store bf16 (h_bf)
// MODE 1: relu((1-b)*fsum + b*acc + bias)     -> store bf16 (res_bf)
// MODE 2: relu((1-b)*fsum + b*acc + bias)     -> store f32  (d_out)
template <int MODE>
__global__ __launch_bounds__(256) void gemm_kernel(
    const bf16_t* __restrict__ A, const bf16_t* __restrict__ BT,
    int lda, int K, int M,
    const float* __restrict__ bias,
    const float* __restrict__ aggp, const bf16_t* __restrict__ hp,
    const float* __restrict__ normp, float beta,
    float* __restrict__ outf, bf16_t* __restrict__ outb) {
  __shared__ bf16_t As[128 * 32];
  __shared__ bf16_t Bs[128 * 32];

  const int t = threadIdx.x;
  const int lane = t & 63;
  const int w = t >> 6;
  const int wm = w & 1, wn = w >> 1;
  const int quad = lane >> 4, m16 = lane & 15;
  const int m0 = blockIdx.y * 128;
  const int n0 = blockIdx.x * 128;

  floatx4 acc[4][4] = {};

  for (int k0 = 0; k0 < K; k0 += 32) {
    uint4 ra[2], rb[2];
#pragma unroll
    for (int it = 0; it < 2; ++it) {
      int c = t + it * 256;
      int r = c >> 2, cc = c & 3;
      int kc = cc ^ ((r >> 1) & 3);       // XOR swizzle of 16B chunks
      int row = m0 + r;
      row = row < M ? row : (M - 1);      // clamp OOB rows (discarded at store)
      ra[it] = *(const uint4*)(A + (size_t)row * lda + (k0 + kc * 8));
      rb[it] = *(const uint4*)(BT + (size_t)(n0 + r) * K + (k0 + kc * 8));
    }
    __syncthreads();
#pragma unroll
    for (int it = 0; it < 2; ++it) {
      int c = t + it * 256;
      *(uint4*)(As + c * 8) = ra[it];
      *(uint4*)(Bs + c * 8) = rb[it];
    }
    __syncthreads();

    bf16x8 af[4], bfr[4];
#pragma unroll
    for (int i = 0; i < 4; ++i) {
      int arow = wm * 64 + i * 16 + m16;
      int ac = quad ^ ((arow >> 1) & 3);
      af[i] = *(const bf16x8*)(As + (arow * 4 + ac) * 8);
      int brow = wn * 64 + i * 16 + m16;
      int bc = quad ^ ((brow >> 1) & 3);
      bfr[i] = *(const bf16x8*)(Bs + (brow * 4 + bc) * 8);
    }
#pragma unroll
    for (int i = 0; i < 4; ++i)
#pragma unroll
      for (int j = 0; j < 4; ++j)
        acc[i][j] = __builtin_amdgcn_mfma_f32_16x16x32_bf16(af[i], bfr[j], acc[i][j], 0, 0, 0);
  }

  // epilogue: C/D layout col = lane&15, row = quad*4 + reg
#pragma unroll
  for (int i = 0; i < 4; ++i) {
#pragma unroll
    for (int j = 0; j < 4; ++j) {
      int col = n0 + wn * 64 + j * 16 + m16;
      float bv = bias[col];
#pragma unroll
      for (int p = 0; p < 4; ++p) {
        int row = m0 + wm * 64 + i * 16 + quad * 4 + p;
        if (row < M) {
          size_t idx = (size_t)row * DD + col;
          float v = acc[i][j][p];
          if constexpr (MODE == 0) {
            outb[idx] = (bf16_t)(v + bv);
          } else {
            float fsum = 0.9f * normp[row] * aggp[idx] + 0.1f * (float)hp[idx];
            float r = (1.0f - beta) * fsum + beta * v + bv;
            r = fmaxf(r, 0.0f);
            if constexpr (MODE == 1) outb[idx] = (bf16_t)r;
            else outf[idx] = r;
          }
        }
      }
    }
  }
}

extern "C" void kernel_launch(void* const* d_in, const int* in_sizes, int n_in,
                              void* d_out, int out_size, void* d_ws, size_t ws_size,
                              hipStream_t stream) {
  const float* feat = (const float*)d_in[0];
  const int* src = (const int*)d_in[1];
  const int* dst = (const int*)d_in[2];
  const float* fc_w = (const float*)d_in[3];
  const float* fc_b = (const float*)d_in[4];
  const float* w1_1 = (const float*)d_in[5];
  const float* w2_1 = (const float*)d_in[6];
  const float* b_1  = (const float*)d_in[7];
  const float* w1_2 = (const float*)d_in[8];
  const float* w2_2 = (const float*)d_in[9];
  const float* b_2  = (const float*)d_in[10];
  float* out = (float*)d_out;

  char* ws = (char*)d_ws;
  size_t off = 0;
  auto alloc = [&](size_t bytes) {
    char* p = ws + off;
    off += (bytes + 255) & ~(size_t)255;
    return p;
  };
  const size_t NDf = (size_t)NN * DD;               // 10.24M elements
  float*  agg    = (float*)alloc(NDf * sizeof(float));          // 40.96 MB
  bf16_t* h_bf   = (bf16_t*)alloc(NDf * sizeof(bf16_t));        // 20.48 MB
  bf16_t* res_bf = (bf16_t*)alloc(NDf * sizeof(bf16_t));        // 20.48 MB
  bf16_t* featb  = (bf16_t*)alloc(NDf * sizeof(bf16_t));        // 20.48 MB
  bf16_t* Acat   = (bf16_t*)alloc((size_t)NN * 1024 * sizeof(bf16_t));  // 40.96 MB
  bf16_t* BW0    = (bf16_t*)alloc((size_t)512 * 512 * sizeof(bf16_t));
  bf16_t* BT1    = (bf16_t*)alloc((size_t)512 * 1024 * sizeof(bf16_t));
  bf16_t* BT2    = (bf16_t*)alloc((size_t)512 * 1024 * sizeof(bf16_t));
  float*  deg    = (float*)alloc((size_t)NN * sizeof(float));
  float*  nrm    = (float*)alloc((size_t)NN * sizeof(float));

  // degree + norm
  hipMemsetAsync(deg, 0, (size_t)NN * sizeof(float), stream);
  deg_kernel<<<(EE + 255) / 256, 256, 0, stream>>>(dst, deg, EE);
  norm_kernel<<<(NN + 255) / 256, 256, 0, stream>>>(deg, nrm, NN);

  // input conversions: feat -> bf16, fc_w -> bf16 (already B^T layout)
  cvt_kernel<<<(int)(NDf / 4 / 256), 256, 0, stream>>>(feat, featb, (int)(NDf / 4));
  cvt_kernel<<<(512 * 512 / 4) / 256, 256, 0, stream>>>(fc_w, BW0, 512 * 512 / 4);

  // weight transposes+convert for layer GEMMs
  transpose_cat<<<dim3(16, 32), dim3(32, 8), 0, stream>>>(w1_1, w2_1, BT1, 1024);
  transpose_cat<<<dim3(16, 32), dim3(32, 8), 0, stream>>>(w1_2, w2_2, BT2, 1024);

  dim3 ggrid(4, 157);  // 512/128 n-tiles, ceil(20000/128) m-tiles

  // h = feat @ fc_w^T + fc_b   (store bf16)
  gemm_kernel<0><<<ggrid, 256, 0, stream>>>(featb, BW0, 512, 512, NN, fc_b,
                                            nullptr, nullptr, nullptr, 0.0f, nullptr, h_bf);

  // ---- layer 1 ----
  hipMemsetAsync(agg, 0, NDf * sizeof(float), stream);
  scatter_kernel<<<EE, 256, 0, stream>>>(h_bf, nrm, src, dst, agg);
  prep_kernel<<<(int)(NDf / 256), 256, 0, stream>>>(agg, h_bf, nrm, Acat);
  gemm_kernel<1><<<ggrid, 256, 0, stream>>>(Acat, BT1, 1024, 1024, NN, b_1,
                                            agg, h_bf, nrm, BETA1, nullptr, res_bf);

  // ---- layer 2 ----
  hipMemsetAsync(agg, 0, NDf * sizeof(float), stream);
  scatter_kernel<<<EE, 256, 0, stream>>>(res_bf, nrm, src, dst, agg);
  prep_kernel<<<(int)(NDf / 256), 256, 0, stream>>>(agg, h_bf, nrm, Acat);
  gemm_kernel<2><<<ggrid, 256, 0, stream>>>(Acat, BT2, 1024, 1024, NN, b_2,
                                            agg, h_bf, nrm, BETA2, out, nullptr);
}

// Round 3
// 694.693 us; speedup vs baseline: 3.7799x; 3.7799x over previous
//
#include <hip/hip_runtime.h>
#include <hip/hip_bf16.h>
#include <stdint.h>
#include <stddef.h>

typedef __bf16 bf16_t;
typedef __bf16 bf16x4 __attribute__((ext_vector_type(4)));
typedef __bf16 bf16x8 __attribute__((ext_vector_type(8)));
typedef float floatx4 __attribute__((ext_vector_type(4)));

#define NN 20000
#define EE 320000
#define DD 512
#define BETA1 0.6931471805599453f
#define BETA2 0.40546510810816444f

// ---------------- degree (int) ----------------
__global__ void deg_kernel(const int* __restrict__ dst, int* __restrict__ deg, int E) {
  int e = blockIdx.x * 256 + threadIdx.x;
  if (e < E) atomicAdd(&deg[dst[e]], 1);
}

__global__ void norm_kernel(const int* __restrict__ deg, float* __restrict__ nrm, int n) {
  int i = blockIdx.x * 256 + threadIdx.x;
  if (i < n) nrm[i] = 1.0f / sqrtf(fmaxf((float)deg[i], 1.0f));
}

// ------------- exclusive scan of deg -> row_ptr, cursor (single block) -------
__global__ void scan_kernel(const int* __restrict__ deg, int* __restrict__ row_ptr,
                            int* __restrict__ cursor, int n) {
  __shared__ int sdata[1024];
  __shared__ int carry;
  if (threadIdx.x == 0) carry = 0;
  __syncthreads();
  for (int base = 0; base < n; base += 1024) {
    int i = base + threadIdx.x;
    int v = (i < n) ? deg[i] : 0;
    sdata[threadIdx.x] = v;
    __syncthreads();
#pragma unroll
    for (int offs = 1; offs < 1024; offs <<= 1) {
      int tv = (threadIdx.x >= offs) ? sdata[threadIdx.x - offs] : 0;
      __syncthreads();
      sdata[threadIdx.x] += tv;
      __syncthreads();
    }
    int excl = sdata[threadIdx.x] - v + carry;
    if (i < n) { row_ptr[i] = excl; cursor[i] = excl; }
    __syncthreads();
    if (threadIdx.x == 1023) carry += sdata[1023];
    __syncthreads();
  }
  if (threadIdx.x == 0) row_ptr[n] = carry;
}

// ------------- bucket fill: esrc[cursor[dst[e]]++] = src[e] ----------------
__global__ void bucket_kernel(const int* __restrict__ src, const int* __restrict__ dst,
                              int* __restrict__ cursor, int* __restrict__ esrc, int E) {
  int e = blockIdx.x * 256 + threadIdx.x;
  if (e < E) {
    int pos = atomicAdd(&cursor[dst[e]], 1);
    esrc[pos] = src[e];
  }
}

// ---------------- f32 -> bf16 convert (4 elems/thread) ----------------
__global__ void cvt_kernel(const float* __restrict__ in, bf16_t* __restrict__ out, int n4) {
  int i = blockIdx.x * 256 + threadIdx.x;
  if (i < n4) {
    float4 v = ((const float4*)in)[i];
    bf16x4 o = {(bf16_t)v.x, (bf16_t)v.y, (bf16_t)v.z, (bf16_t)v.w};
    ((bf16x4*)out)[i] = o;
  }
}

// -------- build BT = [W1; W2]^T (bf16), BT[n][k], n<512, k<K; W* are f32 -----
__global__ void transpose_cat(const float* __restrict__ W1, const float* __restrict__ W2,
                              bf16_t* __restrict__ BT, int K) {
  __shared__ bf16_t tile[32][33];
  int k0 = blockIdx.y * 32;
  int n0 = blockIdx.x * 32;
  int tx = threadIdx.x, ty = threadIdx.y;
  const float* W = (k0 < 512) ? W1 : W2;
  int kk = (k0 < 512) ? k0 : (k0 - 512);
#pragma unroll
  for (int i = 0; i < 32; i += 8)
    tile[ty + i][tx] = (bf16_t)W[(size_t)(kk + ty + i) * 512 + n0 + tx];
  __syncthreads();
#pragma unroll
  for (int i = 0; i < 32; i += 8)
    BT[(size_t)(n0 + ty + i) * K + k0 + tx] = tile[tx][ty + i];
}

// ------------- CSR aggregate: one wave per dst node, lane owns 8 dims --------
// f = 0.9 * nrm[node] * sum_{e in bucket(node)} nrm[src] * hin[src]
// Acat[node][0:512] = bf16(f);  fs[node][:] = f + 0.1*h0[node][:]
__global__ __launch_bounds__(256) void aggregate_kernel(
    const bf16_t* __restrict__ hin, const bf16_t* __restrict__ h0,
    const float* __restrict__ nrm,
    const int* __restrict__ row_ptr, const int* __restrict__ esrc,
    bf16_t* __restrict__ Acat, float* __restrict__ fs) {
  int node = blockIdx.x * 4 + (threadIdx.x >> 6);
  if (node >= NN) return;
  int lane = threadIdx.x & 63;
  int beg = row_ptr[node], end = row_ptr[node + 1];

  float acc[8] = {};
  bf16x8 v = {};
  float ns = 0.0f;
  int e = beg;
  if (e < end) {
    int s = esrc[e];
    ns = nrm[s];
    v = *(const bf16x8*)(hin + (size_t)s * DD + lane * 8);
  }
  while (e < end) {
    bf16x8 vn = v;
    float nsn = ns;
    int en = e + 1;
    if (en < end) {                 // prefetch next row while accumulating
      int sn = esrc[en];
      nsn = nrm[sn];
      vn = *(const bf16x8*)(hin + (size_t)sn * DD + lane * 8);
    }
#pragma unroll
    for (int k = 0; k < 8; ++k) acc[k] += ns * (float)v[k];
    v = vn; ns = nsn; e = en;
  }

  float nd = 0.9f * nrm[node];
  bf16x8 h0v = *(const bf16x8*)(h0 + (size_t)node * DD + lane * 8);
  bf16x8 ob;
  float f8[8];
#pragma unroll
  for (int k = 0; k < 8; ++k) {
    float f = nd * acc[k];
    ob[k] = (bf16_t)f;
    f8[k] = f + 0.1f * (float)h0v[k];
  }
  *(bf16x8*)(Acat + (size_t)node * 1024 + lane * 8) = ob;
  *(float4*)(fs + (size_t)node * DD + lane * 8) = *(float4*)f8;
  *(float4*)(fs + (size_t)node * DD + lane * 8 + 4) = *(float4*)(f8 + 4);
}

// ------------- write Acat second half: bf16(0.1*h)  (layer-invariant) --------
__global__ void acat_h_kernel(const bf16_t* __restrict__ h, bf16_t* __restrict__ Acat) {
  int idx = blockIdx.x * 256 + threadIdx.x;  // over NN*DD/8
  int i = idx >> 6, d = (idx & 63) * 8;
  bf16x8 hv = *(const bf16x8*)(h + (size_t)i * DD + d);
  bf16x8 o;
#pragma unroll
  for (int k = 0; k < 8; ++k) o[k] = (bf16_t)(0.1f * (float)hv[k]);
  *(bf16x8*)(Acat + (size_t)i * 1024 + 512 + d) = o;
}

// -------- GEMM: C = A(MxK,bf16) @ B(Kx512), B given transposed BT[n][k] ------
// MODE 0: h = acc + bias                          -> store bf16 (h_bf)
// MODE 1: relu((1-b)*fs + b*acc + bias)           -> store bf16 (res_bf)
// MODE 2: relu((1-b)*fs + b*acc + bias)           -> store f32  (d_out)
template <int MODE>
__global__ __launch_bounds__(256) void gemm_kernel(
    const bf16_t* __restrict__ A, const bf16_t* __restrict__ BT,
    int lda, int K, int M,
    const float* __restrict__ bias,
    const float* __restrict__ fs, float beta,
    float* __restrict__ outf, bf16_t* __restrict__ outb) {
  __shared__ bf16_t As[128 * 32];
  __shared__ bf16_t Bs[128 * 32];

  const int t = threadIdx.x;
  const int lane = t & 63;
  const int w = t >> 6;
  const int wm = w & 1, wn = w >> 1;
  const int quad = lane >> 4, m16 = lane & 15;
  const int m0 = blockIdx.y * 128;
  const int n0 = blockIdx.x * 128;

  floatx4 acc[4][4] = {};

  for (int k0 = 0; k0 < K; k0 += 32) {
    uint4 ra[2], rb[2];
#pragma unroll
    for (int it = 0; it < 2; ++it) {
      int c = t + it * 256;
      int r = c >> 2, cc = c & 3;
      int kc = cc ^ ((r >> 1) & 3);       // XOR swizzle of 16B chunks
      int row = m0 + r;
      row = row < M ? row : (M - 1);      // clamp OOB rows (discarded at store)
      ra[it] = *(const uint4*)(A + (size_t)row * lda + (k0 + kc * 8));
      rb[it] = *(const uint4*)(BT + (size_t)(n0 + r) * K + (k0 + kc * 8));
    }
    __syncthreads();
#pragma unroll
    for (int it = 0; it < 2; ++it) {
      int c = t + it * 256;
      *(uint4*)(As + c * 8) = ra[it];
      *(uint4*)(Bs + c * 8) = rb[it];
    }
    __syncthreads();

    bf16x8 af[4], bfr[4];
#pragma unroll
    for (int i = 0; i < 4; ++i) {
      int arow = wm * 64 + i * 16 + m16;
      int ac = quad ^ ((arow >> 1) & 3);
      af[i] = *(const bf16x8*)(As + (arow * 4 + ac) * 8);
      int brow = wn * 64 + i * 16 + m16;
      int bc = quad ^ ((brow >> 1) & 3);
      bfr[i] = *(const bf16x8*)(Bs + (brow * 4 + bc) * 8);
    }
#pragma unroll
    for (int i = 0; i < 4; ++i)
#pragma unroll
      for (int j = 0; j < 4; ++j)
        acc[i][j] = __builtin_amdgcn_mfma_f32_16x16x32_bf16(af[i], bfr[j], acc[i][j], 0, 0, 0);
  }

  // epilogue: C/D layout col = lane&15, row = quad*4 + reg
#pragma unroll
  for (int i = 0; i < 4; ++i) {
#pragma unroll
    for (int j = 0; j < 4; ++j) {
      int col = n0 + wn * 64 + j * 16 + m16;
      float bv = bias[col];
#pragma unroll
      for (int p = 0; p < 4; ++p) {
        int row = m0 + wm * 64 + i * 16 + quad * 4 + p;
        if (row < M) {
          size_t idx = (size_t)row * DD + col;
          float v = acc[i][j][p];
          if constexpr (MODE == 0) {
            outb[idx] = (bf16_t)(v + bv);
          } else {
            float r = (1.0f - beta) * fs[idx] + beta * v + bv;
            r = fmaxf(r, 0.0f);
            if constexpr (MODE == 1) outb[idx] = (bf16_t)r;
            else outf[idx] = r;
          }
        }
      }
    }
  }
}

extern "C" void kernel_launch(void* const* d_in, const int* in_sizes, int n_in,
                              void* d_out, int out_size, void* d_ws, size_t ws_size,
                              hipStream_t stream) {
  const float* feat = (const float*)d_in[0];
  const int* src = (const int*)d_in[1];
  const int* dst = (const int*)d_in[2];
  const float* fc_w = (const float*)d_in[3];
  const float* fc_b = (const float*)d_in[4];
  const float* w1_1 = (const float*)d_in[5];
  const float* w2_1 = (const float*)d_in[6];
  const float* b_1  = (const float*)d_in[7];
  const float* w1_2 = (const float*)d_in[8];
  const float* w2_2 = (const float*)d_in[9];
  const float* b_2  = (const float*)d_in[10];
  float* out = (float*)d_out;

  char* ws = (char*)d_ws;
  size_t off = 0;
  auto alloc = [&](size_t bytes) {
    char* p = ws + off;
    off += (bytes + 255) & ~(size_t)255;
    return p;
  };
  const size_t NDf = (size_t)NN * DD;               // 10.24M elements
  float*  fs     = (float*)alloc(NDf * sizeof(float));          // 40.96 MB
  bf16_t* h_bf   = (bf16_t*)alloc(NDf * sizeof(bf16_t));        // 20.48 MB
  bf16_t* res_bf = (bf16_t*)alloc(NDf * sizeof(bf16_t));        // 20.48 MB
  bf16_t* featb  = (bf16_t*)alloc(NDf * sizeof(bf16_t));        // 20.48 MB
  bf16_t* Acat   = (bf16_t*)alloc((size_t)NN * 1024 * sizeof(bf16_t));  // 40.96 MB
  bf16_t* BW0    = (bf16_t*)alloc((size_t)512 * 512 * sizeof(bf16_t));
  bf16_t* BT1    = (bf16_t*)alloc((size_t)512 * 1024 * sizeof(bf16_t));
  bf16_t* BT2    = (bf16_t*)alloc((size_t)512 * 1024 * sizeof(bf16_t));
  int*    deg     = (int*)alloc((size_t)NN * sizeof(int));
  float*  nrm     = (float*)alloc((size_t)NN * sizeof(float));
  int*    row_ptr = (int*)alloc((size_t)(NN + 1) * sizeof(int));
  int*    cursor  = (int*)alloc((size_t)NN * sizeof(int));
  int*    esrc    = (int*)alloc((size_t)EE * sizeof(int));

  // degree + norm + CSR buckets
  hipMemsetAsync(deg, 0, (size_t)NN * sizeof(int), stream);
  deg_kernel<<<(EE + 255) / 256, 256, 0, stream>>>(dst, deg, EE);
  norm_kernel<<<(NN + 255) / 256, 256, 0, stream>>>(deg, nrm, NN);
  scan_kernel<<<1, 1024, 0, stream>>>(deg, row_ptr, cursor, NN);
  bucket_kernel<<<(EE + 255) / 256, 256, 0, stream>>>(src, dst, cursor, esrc, EE);

  // input conversions: feat -> bf16, fc_w -> bf16 (already B^T layout)
  cvt_kernel<<<(int)(NDf / 4 / 256), 256, 0, stream>>>(feat, featb, (int)(NDf / 4));
  cvt_kernel<<<(512 * 512 / 4) / 256, 256, 0, stream>>>(fc_w, BW0, 512 * 512 / 4);

  // weight transposes+convert for layer GEMMs
  transpose_cat<<<dim3(16, 32), dim3(32, 8), 0, stream>>>(w1_1, w2_1, BT1, 1024);
  transpose_cat<<<dim3(16, 32), dim3(32, 8), 0, stream>>>(w1_2, w2_2, BT2, 1024);

  dim3 ggrid(4, 157);  // 512/128 n-tiles, ceil(20000/128) m-tiles

  // h = feat @ fc_w^T + fc_b   (store bf16)
  gemm_kernel<0><<<ggrid, 256, 0, stream>>>(featb, BW0, 512, 512, NN, fc_b,
                                            nullptr, 0.0f, nullptr, h_bf);

  // Acat second half = bf16(0.1*h) — layer-invariant, write once
  acat_h_kernel<<<(int)(NDf / 8 / 256), 256, 0, stream>>>(h_bf, Acat);

  // ---- layer 1 ----
  aggregate_kernel<<<(NN + 3) / 4, 256, 0, stream>>>(h_bf, h_bf, nrm, row_ptr, esrc, Acat, fs);
  gemm_kernel<1><<<ggrid, 256, 0, stream>>>(Acat, BT1, 1024, 1024, NN, b_1,
                                            fs, BETA1, nullptr, res_bf);

  // ---- layer 2 ----
  aggregate_kernel<<<(NN + 3) / 4, 256, 0, stream>>>(res_bf, h_bf, nrm, row_ptr, esrc, Acat, fs);
  gemm_kernel<2><<<ggrid, 256, 0, stream>>>(Acat, BT2, 1024, 1024, NN, b_2,
                                            fs, BETA2, out, nullptr);
}

// Round 4
// 464.786 us; speedup vs baseline: 5.6496x; 1.4947x over previous
//
#include <hip/hip_runtime.h>
#include <hip/hip_bf16.h>
#include <stdint.h>
#include <stddef.h>

typedef __bf16 bf16_t;
typedef __bf16 bf16x4 __attribute__((ext_vector_type(4)));
typedef __bf16 bf16x8 __attribute__((ext_vector_type(8)));
typedef float floatx4 __attribute__((ext_vector_type(4)));

#define NN 20000
#define EE 320000
#define DD 512
#define BETA1 0.6931471805599453f
#define BETA2 0.40546510810816444f

// async global->LDS, 16B per lane. LDS dest must be wave-uniform base + lane*16.
__device__ __forceinline__ void gload16(const bf16_t* g, bf16_t* l) {
  __builtin_amdgcn_global_load_lds((const __attribute__((address_space(1))) uint32_t*)g,
                                   (__attribute__((address_space(3))) uint32_t*)l, 16, 0, 0);
}

// ---------------- degree (int) ----------------
__global__ void deg_kernel(const int* __restrict__ dst, int* __restrict__ deg, int E) {
  int e = blockIdx.x * 256 + threadIdx.x;
  if (e < E) atomicAdd(&deg[dst[e]], 1);
}

__global__ void norm_kernel(const int* __restrict__ deg, float* __restrict__ nrm, int n) {
  int i = blockIdx.x * 256 + threadIdx.x;
  if (i < n) nrm[i] = 1.0f / sqrtf(fmaxf((float)deg[i], 1.0f));
}

// ------------- exclusive scan of deg -> row_ptr, cursor (single block) -------
__global__ void scan_kernel(const int* __restrict__ deg, int* __restrict__ row_ptr,
                            int* __restrict__ cursor, int n) {
  __shared__ int sdata[1024];
  __shared__ int carry;
  if (threadIdx.x == 0) carry = 0;
  __syncthreads();
  for (int base = 0; base < n; base += 1024) {
    int i = base + threadIdx.x;
    int v = (i < n) ? deg[i] : 0;
    sdata[threadIdx.x] = v;
    __syncthreads();
#pragma unroll
    for (int offs = 1; offs < 1024; offs <<= 1) {
      int tv = (threadIdx.x >= offs) ? sdata[threadIdx.x - offs] : 0;
      __syncthreads();
      sdata[threadIdx.x] += tv;
      __syncthreads();
    }
    int excl = sdata[threadIdx.x] - v + carry;
    if (i < n) { row_ptr[i] = excl; cursor[i] = excl; }
    __syncthreads();
    if (threadIdx.x == 1023) carry += sdata[1023];
    __syncthreads();
  }
  if (threadIdx.x == 0) row_ptr[n] = carry;
}

// ------------- bucket fill: esrc[cursor[dst[e]]++] = src[e] ----------------
__global__ void bucket_kernel(const int* __restrict__ src, const int* __restrict__ dst,
                              int* __restrict__ cursor, int* __restrict__ esrc, int E) {
  int e = blockIdx.x * 256 + threadIdx.x;
  if (e < E) {
    int pos = atomicAdd(&cursor[dst[e]], 1);
    esrc[pos] = src[e];
  }
}

// ---------------- f32 -> bf16 convert (4 elems/thread) ----------------
__global__ void cvt_kernel(const float* __restrict__ in, bf16_t* __restrict__ out, int n4) {
  int i = blockIdx.x * 256 + threadIdx.x;
  if (i < n4) {
    float4 v = ((const float4*)in)[i];
    bf16x4 o = {(bf16_t)v.x, (bf16_t)v.y, (bf16_t)v.z, (bf16_t)v.w};
    ((bf16x4*)out)[i] = o;
  }
}

// -------- build BT = [W1; W2]^T (bf16), BT[n][k], n<512, k<K; W* are f32 -----
__global__ void transpose_cat(const float* __restrict__ W1, const float* __restrict__ W2,
                              bf16_t* __restrict__ BT, int K) {
  __shared__ bf16_t tile[32][33];
  int k0 = blockIdx.y * 32;
  int n0 = blockIdx.x * 32;
  int tx = threadIdx.x, ty = threadIdx.y;
  const float* W = (k0 < 512) ? W1 : W2;
  int kk = (k0 < 512) ? k0 : (k0 - 512);
#pragma unroll
  for (int i = 0; i < 32; i += 8)
    tile[ty + i][tx] = (bf16_t)W[(size_t)(kk + ty + i) * 512 + n0 + tx];
  __syncthreads();
#pragma unroll
  for (int i = 0; i < 32; i += 8)
    BT[(size_t)(n0 + ty + i) * K + k0 + tx] = tile[tx][ty + i];
}

// ------------- CSR aggregate: one wave per dst node, lane owns 8 dims --------
// f = 0.9 * nrm[node] * sum_{e in bucket(node)} nrm[src] * hin[src]
// Acat[node][0:512] = bf16(f);  fs[node][:] = f + 0.1*h0[node][:]
__global__ __launch_bounds__(256) void aggregate_kernel(
    const bf16_t* __restrict__ hin, const bf16_t* __restrict__ h0,
    const float* __restrict__ nrm,
    const int* __restrict__ row_ptr, const int* __restrict__ esrc,
    bf16_t* __restrict__ Acat, float* __restrict__ fs) {
  int node = blockIdx.x * 4 + (threadIdx.x >> 6);
  if (node >= NN) return;
  int lane = threadIdx.x & 63;
  int beg = row_ptr[node], end = row_ptr[node + 1];

  float acc[8] = {};
  bf16x8 v = {};
  float ns = 0.0f;
  int e = beg;
  if (e < end) {
    int s = esrc[e];
    ns = nrm[s];
    v = *(const bf16x8*)(hin + (size_t)s * DD + lane * 8);
  }
  while (e < end) {
    bf16x8 vn = v;
    float nsn = ns;
    int en = e + 1;
    if (en < end) {                 // prefetch next row while accumulating
      int sn = esrc[en];
      nsn = nrm[sn];
      vn = *(const bf16x8*)(hin + (size_t)sn * DD + lane * 8);
    }
#pragma unroll
    for (int k = 0; k < 8; ++k) acc[k] += ns * (float)v[k];
    v = vn; ns = nsn; e = en;
  }

  float nd = 0.9f * nrm[node];
  bf16x8 h0v = *(const bf16x8*)(h0 + (size_t)node * DD + lane * 8);
  bf16x8 ob;
  float f8[8];
#pragma unroll
  for (int k = 0; k < 8; ++k) {
    float f = nd * acc[k];
    ob[k] = (bf16_t)f;
    f8[k] = f + 0.1f * (float)h0v[k];
  }
  *(bf16x8*)(Acat + (size_t)node * 1024 + lane * 8) = ob;
  *(float4*)(fs + (size_t)node * DD + lane * 8) = *(float4*)f8;
  *(float4*)(fs + (size_t)node * DD + lane * 8 + 4) = *(float4*)(f8 + 4);
}

// -------- GEMM: C = A(MxK,bf16) @ B(Kx512), B given transposed BT[n][k] ------
// Tile 64x128, 4 waves (2x2), dbuf LDS via global_load_lds, 1 barrier/iter.
// MODE 0: h = acc + bias  -> h_bf (bf16) AND acat2[row*1024+512+col] = 0.1*h
// MODE 1: relu((1-b)*fs + b*acc + bias)  -> bf16 outb
// MODE 2: relu((1-b)*fs + b*acc + bias)  -> f32  outf
template <int MODE>
__global__ __launch_bounds__(256) void gemm_kernel(
    const bf16_t* __restrict__ A, const bf16_t* __restrict__ BT,
    int lda, int ldb, int K, int M,
    const float* __restrict__ bias,
    const float* __restrict__ fs, float beta,
    float* __restrict__ outf, bf16_t* __restrict__ outb,
    bf16_t* __restrict__ acat2) {
  __shared__ bf16_t As[2][64 * 32];    // 4 KB per buf
  __shared__ bf16_t Bs[2][128 * 32];   // 8 KB per buf

  const int t = threadIdx.x;
  const int lane = t & 63;
  const int w = t >> 6;
  const int wm = w & 1, wn = w >> 1;
  const int quad = lane >> 4, m16 = lane & 15;
  const int m0 = blockIdx.y * 64;
  const int n0 = blockIdx.x * 128;

  // staging addresses: chunk c -> row r=c>>2, 16B-chunk kc = (c&3) ^ ((r>>1)&3)
  const int ar = t >> 2;
  const int akc = (t & 3) ^ ((ar >> 1) & 3);
  int arow_g = m0 + ar; arow_g = arow_g < M ? arow_g : M - 1;  // clamp OOB
  const bf16_t* agp  = A  + (size_t)arow_g * lda + akc * 8;
  const bf16_t* bgp0 = BT + (size_t)(n0 + ar) * ldb + akc * 8;
  const bf16_t* bgp1 = BT + (size_t)(n0 + 64 + ar) * ldb + akc * 8;

  floatx4 acc[2][4] = {};
  const int niter = K >> 5;

  // stage buffer 0
  gload16(agp,  &As[0][t * 8]);
  gload16(bgp0, &Bs[0][t * 8]);
  gload16(bgp1, &Bs[0][(t + 256) * 8]);

  for (int kt = 0; kt < niter; ++kt) {
    __syncthreads();   // drains buf kt's loads (issued one iter ago)
    const int b = kt & 1;
    if (kt + 1 < niter) {        // prefetch next buffer; lands by next barrier
      const int nb = b ^ 1;
      const int ko = (kt + 1) * 32;
      gload16(agp + ko,  &As[nb][t * 8]);
      gload16(bgp0 + ko, &Bs[nb][t * 8]);
      gload16(bgp1 + ko, &Bs[nb][(t + 256) * 8]);
    }

    bf16x8 af[2], bfr[4];
#pragma unroll
    for (int i = 0; i < 2; ++i) {
      int arow = wm * 32 + i * 16 + m16;
      int ac = quad ^ ((arow >> 1) & 3);
      af[i] = *(const bf16x8*)(&As[b][(arow * 4 + ac) * 8]);
    }
#pragma unroll
    for (int j = 0; j < 4; ++j) {
      int brow = wn * 64 + j * 16 + m16;
      int bc = quad ^ ((brow >> 1) & 3);
      bfr[j] = *(const bf16x8*)(&Bs[b][(brow * 4 + bc) * 8]);
    }
#pragma unroll
    for (int i = 0; i < 2; ++i)
#pragma unroll
      for (int j = 0; j < 4; ++j)
        acc[i][j] = __builtin_amdgcn_mfma_f32_16x16x32_bf16(af[i], bfr[j], acc[i][j], 0, 0, 0);
  }

  // epilogue: C/D layout col = lane&15, row = quad*4 + reg
#pragma unroll
  for (int i = 0; i < 2; ++i) {
#pragma unroll
    for (int j = 0; j < 4; ++j) {
      int col = n0 + wn * 64 + j * 16 + m16;
      float bv = bias[col];
#pragma unroll
      for (int p = 0; p < 4; ++p) {
        int row = m0 + wm * 32 + i * 16 + quad * 4 + p;
        if (row < M) {
          size_t idx = (size_t)row * DD + col;
          float v = acc[i][j][p];
          if constexpr (MODE == 0) {
            float hv = v + bv;
            outb[idx] = (bf16_t)hv;
            acat2[(size_t)row * 1024 + 512 + col] = (bf16_t)(0.1f * hv);
          } else {
            float r = (1.0f - beta) * fs[idx] + beta * v + bv;
            r = fmaxf(r, 0.0f);
            if constexpr (MODE == 1) outb[idx] = (bf16_t)r;
            else outf[idx] = r;
          }
        }
      }
    }
  }
}

extern "C" void kernel_launch(void* const* d_in, const int* in_sizes, int n_in,
                              void* d_out, int out_size, void* d_ws, size_t ws_size,
                              hipStream_t stream) {
  const float* feat = (const float*)d_in[0];
  const int* src = (const int*)d_in[1];
  const int* dst = (const int*)d_in[2];
  const float* fc_w = (const float*)d_in[3];
  const float* fc_b = (const float*)d_in[4];
  const float* w1_1 = (const float*)d_in[5];
  const float* w2_1 = (const float*)d_in[6];
  const float* b_1  = (const float*)d_in[7];
  const float* w1_2 = (const float*)d_in[8];
  const float* w2_2 = (const float*)d_in[9];
  const float* b_2  = (const float*)d_in[10];
  float* out = (float*)d_out;

  char* ws = (char*)d_ws;
  size_t off = 0;
  auto alloc = [&](size_t bytes) {
    char* p = ws + off;
    off += (bytes + 255) & ~(size_t)255;
    return p;
  };
  const size_t NDf = (size_t)NN * DD;               // 10.24M elements
  float*  fs     = (float*)alloc(NDf * sizeof(float));          // 40.96 MB
  bf16_t* h_bf   = (bf16_t*)alloc(NDf * sizeof(bf16_t));        // 20.48 MB
  bf16_t* res_bf = (bf16_t*)alloc(NDf * sizeof(bf16_t));        // 20.48 MB
  bf16_t* featb  = (bf16_t*)alloc(NDf * sizeof(bf16_t));        // 20.48 MB
  bf16_t* Acat   = (bf16_t*)alloc((size_t)NN * 1024 * sizeof(bf16_t));  // 40.96 MB
  bf16_t* BW0    = (bf16_t*)alloc((size_t)512 * 512 * sizeof(bf16_t));
  bf16_t* BT1    = (bf16_t*)alloc((size_t)512 * 1024 * sizeof(bf16_t));
  bf16_t* BT2    = (bf16_t*)alloc((size_t)512 * 1024 * sizeof(bf16_t));
  int*    deg     = (int*)alloc((size_t)NN * sizeof(int));
  float*  nrm     = (float*)alloc((size_t)NN * sizeof(float));
  int*    row_ptr = (int*)alloc((size_t)(NN + 1) * sizeof(int));
  int*    cursor  = (int*)alloc((size_t)NN * sizeof(int));
  int*    esrc    = (int*)alloc((size_t)EE * sizeof(int));

  // degree + norm + CSR buckets
  hipMemsetAsync(deg, 0, (size_t)NN * sizeof(int), stream);
  deg_kernel<<<(EE + 255) / 256, 256, 0, stream>>>(dst, deg, EE);
  norm_kernel<<<(NN + 255) / 256, 256, 0, stream>>>(deg, nrm, NN);
  scan_kernel<<<1, 1024, 0, stream>>>(deg, row_ptr, cursor, NN);
  bucket_kernel<<<(EE + 255) / 256, 256, 0, stream>>>(src, dst, cursor, esrc, EE);

  // input conversions: feat -> bf16, fc_w -> bf16 (already B^T layout)
  cvt_kernel<<<(int)(NDf / 4 / 256), 256, 0, stream>>>(feat, featb, (int)(NDf / 4));
  cvt_kernel<<<(512 * 512 / 4) / 256, 256, 0, stream>>>(fc_w, BW0, 512 * 512 / 4);

  // weight transposes+convert for layer GEMMs
  transpose_cat<<<dim3(16, 32), dim3(32, 8), 0, stream>>>(w1_1, w2_1, BT1, 1024);
  transpose_cat<<<dim3(16, 32), dim3(32, 8), 0, stream>>>(w1_2, w2_2, BT2, 1024);

  dim3 ggrid(4, 313);  // 512/128 n-tiles, ceil(20000/64) m-tiles

  // h = feat @ fc_w^T + fc_b  (stores h_bf AND Acat second half = 0.1*h)
  gemm_kernel<0><<<ggrid, 256, 0, stream>>>(featb, BW0, 512, 512, 512, NN, fc_b,
                                            nullptr, 0.0f, nullptr, h_bf, Acat);

  // ---- layer 1 ----
  aggregate_kernel<<<(NN + 3) / 4, 256, 0, stream>>>(h_bf, h_bf, nrm, row_ptr, esrc, Acat, fs);
  gemm_kernel<1><<<ggrid, 256, 0, stream>>>(Acat, BT1, 1024, 1024, 1024, NN, b_1,
                                            fs, BETA1, nullptr, res_bf, nullptr);

  // ---- layer 2 ----
  aggregate_kernel<<<(NN + 3) / 4, 256, 0, stream>>>(res_bf, h_bf, nrm, row_ptr, esrc, Acat, fs);
  gemm_kernel<2><<<ggrid, 256, 0, stream>>>(Acat, BT2, 1024, 1024, 1024, NN, b_2,
                                            fs, BETA2, out, nullptr, nullptr);
}